// Round 7
// baseline (6994.124 us; speedup 1.0000x reference)
//
#include <hip/hip_runtime.h>

typedef short bf16x8 __attribute__((ext_vector_type(8)));
typedef float f32x4 __attribute__((ext_vector_type(4)));
typedef unsigned short u16;
typedef unsigned int u32;
typedef unsigned long long u64;

static constexpr int B = 2048, S = 128, D = 128, H = 256;
static constexpr size_t PH = (size_t)B * H;

// LDS layout (u16 units), 104 KiB total. All tiles are [rows][64] -> 128B rows.
//   Wb: 2 bufs x [128][64]  = 2*8192   [0, 16384)
//   Wp: [4][16][64]         = 4096     [16384, 20480)
//   Ahi: 2 bufs x [128][64] = 2*8192   [20480, 36864)
//   Alo: 2 bufs x [128][64] = 2*8192   [36864, 53248)
#define L_WB   0
#define L_WP   16384
#define L_AHI  20480
#define L_ALO  36864
#define L_TOT  53248

__device__ __forceinline__ u16 f2bf(float x){ u32 u=__float_as_uint(x); return (u16)((u + 0x7fffu + ((u>>16)&1u))>>16); }
__device__ __forceinline__ float bf2f(u16 h){ return __uint_as_float(((u32)h)<<16); }
__device__ __forceinline__ float fsig(float x){ return 1.0f/(1.0f+__expf(-x)); }
__device__ __forceinline__ float ftanh(float x){ return 1.0f - 2.0f/(__expf(2.0f*x)+1.0f); }

__device__ __forceinline__ void gl_lds16(const void* g, const u16* l){
  __builtin_amdgcn_global_load_lds((const __attribute__((address_space(1))) void*)g,
      (__attribute__((address_space(3))) void*)l, 16, 0, 0);
}
__device__ __forceinline__ u64 ald64(const u32* p){
  return __hip_atomic_load((const u64*)p, __ATOMIC_RELAXED, __HIP_MEMORY_SCOPE_AGENT);
}
__device__ __forceinline__ u32 ald32(const u32* p){
  return __hip_atomic_load(p, __ATOMIC_RELAXED, __HIP_MEMORY_SCOPE_AGENT);
}
__device__ __forceinline__ void ast32(u32* p, u32 v){
  __hip_atomic_store(p, v, __ATOMIC_RELAXED, __HIP_MEMORY_SCOPE_AGENT);
}

__global__ __launch_bounds__(256) void cvtk(const float* __restrict__ s, u16* __restrict__ d, int n){
  int i = (blockIdx.x*256 + threadIdx.x)*4;
  if (i+3 < n){
    float4 v = *(const float4*)(s+i);
    d[i]=f2bf(v.x); d[i+1]=f2bf(v.y); d[i+2]=f2bf(v.z); d[i+3]=f2bf(v.w);
  }
}
__global__ __launch_bounds__(256) void addk(const float* __restrict__ a, const float* __restrict__ b,
                                            float* __restrict__ o, int n){
  int i = blockIdx.x*256 + threadIdx.x; if (i<n) o[i]=a[i]+b[i];
}

// One LSTM-layer (or proj-fused) phase job. Tiles are 64 elements of K.
struct Ph {
  const float* xf; int t;            // fp32 x source (enc L0, tiles < n1) or null
  const u32 *A1, *A2; int n1, n2;    // packed hi|lo u32 planes; K64-tile counts
  const u16 *W1, *W2; int ldw1, ldw2;
  size_t gb;                         // batch-row base (M = 64*MF rows)
  const float* bs;                   // fused bias (4H fp32)
  u32* outP;                         // h output plane (packed hi|lo)
  int doprj; const float* bout; float* out; int tau;
};

// 8 waves. MF=2: 128 rows x 128 z-cols; MF=1: 64 rows x 128 z-cols.
// m-group = w>>1, n-half = w&1; frag q = gate q at j = n*32+(w&1)*16+lr.
template<int MF>
__device__ __forceinline__ void run_layer(u16* lds, const Ph& J,
    const int tid, const int w, const int lr, const int lc, const int n,
    float (&cst)[MF][4])
{
  const int nt = J.n1 + J.n2;
  const int M4 = MF * 256;                   // A-staging threads
  const int srow = tid >> 2, koct = tid & 3;
  const int s1 = koct ^ (srow & 7);
  const int adst = srow*64 + s1*8;           // chunk0; chunk1 = adst ^ 32

  // fragment read offsets (ks=0; ks=1 -> ^32)
  int aoff[MF];
  #pragma unroll
  for (int mf = 0; mf < MF; ++mf){
    const int r = (w>>1)*(16*MF) + mf*16 + lr;
    aoff[mf] = r*64 + ((lc ^ (r & 7))*8);
  }
  int woff[4];
  #pragma unroll
  for (int q = 0; q < 4; ++q){
    const int zr = (w&1)*64 + q*16 + lr;
    woff[q] = zr*64 + ((lc ^ (zr & 7))*8);
  }
  const int poff = lr*64 + ((lc ^ (lr & 7))*8);

  f32x4 acc[MF][4];
  f32x4 accp[MF];
  #pragma unroll
  for (int mf=0; mf<MF; ++mf){
    accp[mf] = (f32x4){0.f,0.f,0.f,0.f};
    #pragma unroll
    for (int q=0; q<4; ++q) acc[mf][q] = (f32x4){0.f,0.f,0.f,0.f};
  }

  u64 rA[8];

  auto issueW = [&](int tile, int wb){
    const u16* Ws; int ldw, k0;
    if (tile < J.n1){ Ws = J.W1; ldw = J.ldw1; k0 = tile*64; }
    else            { Ws = J.W2; ldw = J.ldw2; k0 = (tile - J.n1)*64; }
    #pragma unroll
    for (int p2 = 0; p2 < 2; ++p2){
      const int c = p2*512 + tid;
      const int rl = c >> 3, sl = c & 7;
      const int gs = sl ^ (rl & 7);
      const int f = rl >> 4, r = rl & 15;
      const int zrow = (f & 3)*H + n*32 + ((f >> 2) << 4) + r;
      gl_lds16(Ws + (size_t)zrow*ldw + k0 + gs*8,
               &lds[L_WB + wb*8192 + p2*4096 + (tid>>6)*512]);
    }
  };
  auto issueA = [&](int tile){
    if (tid >= M4) return;
    if (J.xf && tile < J.n1){
      const float* src = J.xf + ((J.gb + srow)*S + J.t)*D + tile*64;
      #pragma unroll
      for (int i = 0; i < 4; ++i) rA[i]   = *(const u64*)(src + koct*8 + 2*i);
      #pragma unroll
      for (int i = 0; i < 4; ++i) rA[4+i] = *(const u64*)(src + (koct+4)*8 + 2*i);
    } else {
      const u32* pln; int k0;
      if (tile < J.n1){ pln = J.A1; k0 = tile*64; }
      else            { pln = J.A2; k0 = (tile - J.n1)*64; }
      const u32* base = pln + (J.gb + srow)*(size_t)H + k0;
      #pragma unroll
      for (int i = 0; i < 4; ++i) rA[i]   = ald64(base + koct*8 + 2*i);
      #pragma unroll
      for (int i = 0; i < 4; ++i) rA[4+i] = ald64(base + (koct+4)*8 + 2*i);
    }
  };
  auto commitA = [&](int tile, int ab){
    if (tid >= M4) return;
    u16 h0[8], l0[8], h1[8], l1[8];
    if (J.xf && tile < J.n1){
      #pragma unroll
      for (int i = 0; i < 4; ++i){
        float fa = __uint_as_float((u32)rA[i]);
        float fb = __uint_as_float((u32)(rA[i] >> 32));
        u16 ha = f2bf(fa); h0[2*i]   = ha; l0[2*i]   = f2bf(fa - bf2f(ha));
        u16 hb = f2bf(fb); h0[2*i+1] = hb; l0[2*i+1] = f2bf(fb - bf2f(hb));
        float fc = __uint_as_float((u32)rA[4+i]);
        float fd = __uint_as_float((u32)(rA[4+i] >> 32));
        u16 hc = f2bf(fc); h1[2*i]   = hc; l1[2*i]   = f2bf(fc - bf2f(hc));
        u16 hd = f2bf(fd); h1[2*i+1] = hd; l1[2*i+1] = f2bf(fd - bf2f(hd));
      }
    } else {
      #pragma unroll
      for (int i = 0; i < 4; ++i){
        u32 e0 = (u32)rA[i],   e1 = (u32)(rA[i]   >> 32);
        u32 e2 = (u32)rA[4+i], e3 = (u32)(rA[4+i] >> 32);
        h0[2*i]   = (u16)(e0 >> 16); l0[2*i]   = (u16)e0;
        h0[2*i+1] = (u16)(e1 >> 16); l0[2*i+1] = (u16)e1;
        h1[2*i]   = (u16)(e2 >> 16); l1[2*i]   = (u16)e2;
        h1[2*i+1] = (u16)(e3 >> 16); l1[2*i+1] = (u16)e3;
      }
    }
    *(bf16x8*)&lds[L_AHI + ab*8192 + adst]        = *(bf16x8*)h0;
    *(bf16x8*)&lds[L_ALO + ab*8192 + adst]        = *(bf16x8*)l0;
    *(bf16x8*)&lds[L_AHI + ab*8192 + (adst ^ 32)] = *(bf16x8*)h1;
    *(bf16x8*)&lds[L_ALO + ab*8192 + (adst ^ 32)] = *(bf16x8*)l1;
  };

  issueW(0, 0);
  issueA(0);
  commitA(0, 0);
  __syncthreads();

  for (int tl = 0; tl < nt; ++tl){
    const int ab = tl & 1;
    if (tl + 1 < nt){ issueW(tl+1, ab^1); issueA(tl+1); }
    // compute tile tl
    #pragma unroll
    for (int ks = 0; ks < 2; ++ks){
      const int kx = ks << 5;   // ^32 on offsets
      bf16x8 ah[MF], al[MF];
      #pragma unroll
      for (int mf = 0; mf < MF; ++mf){
        ah[mf] = *(const bf16x8*)&lds[L_AHI + ab*8192 + (aoff[mf] ^ kx)];
        al[mf] = *(const bf16x8*)&lds[L_ALO + ab*8192 + (aoff[mf] ^ kx)];
      }
      #pragma unroll
      for (int q = 0; q < 4; ++q){
        bf16x8 bq = *(const bf16x8*)&lds[L_WB + ab*8192 + (woff[q] ^ kx)];
        #pragma unroll
        for (int mf = 0; mf < MF; ++mf){
          acc[mf][q] = __builtin_amdgcn_mfma_f32_16x16x32_bf16(ah[mf], bq, acc[mf][q], 0,0,0);
          acc[mf][q] = __builtin_amdgcn_mfma_f32_16x16x32_bf16(al[mf], bq, acc[mf][q], 0,0,0);
        }
      }
      if (J.doprj && (w & 1) == 0 && tl < 4){
        bf16x8 bp = *(const bf16x8*)&lds[L_WP + tl*1024 + (poff ^ kx)];
        #pragma unroll
        for (int mf = 0; mf < MF; ++mf){
          accp[mf] = __builtin_amdgcn_mfma_f32_16x16x32_bf16(ah[mf], bp, accp[mf], 0,0,0);
          accp[mf] = __builtin_amdgcn_mfma_f32_16x16x32_bf16(al[mf], bp, accp[mf], 0,0,0);
        }
      }
    }
    if (tl + 1 < nt) commitA(tl+1, ab^1);
    __syncthreads();
  }

  // epilogue: gates -> c,h ; packed coherent h store
  {
    const int j = n*32 + (w&1)*16 + lr;
    const float b0 = J.bs[j], b1 = J.bs[H+j], b2 = J.bs[2*H+j], b3 = J.bs[3*H+j];
    #pragma unroll
    for (int mf = 0; mf < MF; ++mf){
      #pragma unroll
      for (int r = 0; r < 4; ++r){
        const size_t m = J.gb + (size_t)(w>>1)*(16*MF) + mf*16 + lc*4 + r;
        const float ig = fsig (acc[mf][0][r] + b0);
        const float fg = fsig (acc[mf][1][r] + b1);
        const float gg = ftanh(acc[mf][2][r] + b2);
        const float og = fsig (acc[mf][3][r] + b3);
        const float c  = fg*cst[mf][r] + ig*gg;
        cst[mf][r] = c;
        const float h = og * ftanh(c);
        const u16 hb = f2bf(h);
        const u16 lb = f2bf(h - bf2f(hb));
        ast32(J.outP + m*H + j, ((u32)hb << 16) | lb);
      }
    }
    if (J.doprj && (w & 1) == 0){
      const int col = n*16 + lr;
      const float bo = J.bout[col];
      #pragma unroll
      for (int mf = 0; mf < MF; ++mf){
        #pragma unroll
        for (int r = 0; r < 4; ++r){
          const size_t m = J.gb + (size_t)(w>>1)*(16*MF) + mf*16 + lc*4 + r;
          J.out[(m*S + J.tau)*D + col] = accp[mf][r] + bo;
        }
      }
    }
  }
}

struct GG {
  const float* x;
  const u16* W[9];
  const float* bs; const float* bout;
  u32* P;           // 9 packed planes of B*H u32 (8 live + 1 sink)
  float* out; u32* flags;
};

// planes: 0,1: eh1  2,3: eh2  4,5: dh1  6,7: dh2  8: sink   (r6 parity: h(t) -> (t+1)&1)
__global__ __launch_bounds__(512, 1) void persist(GG g)
{
  __shared__ u16 lds[L_TOT];
  const int tid = threadIdx.x, w = tid>>6, l = tid&63, lr = l&15, lc = l>>4;
  const int bid = blockIdx.x;
  // XCD-locality decode: XCD = bid&7 = idx&7 -> each XCD hosts one (role,n) pair
  const int idx = bid & 15, slice = bid >> 4, role = idx >> 3, n = idx & 7;
  const size_t gb0 = (size_t)slice * 128;
  u32* flg = g.flags + slice*16;
  auto P = [&](int i){ return g.P + (size_t)i * PH; };

  // proj weights resident (8KB, once): [4 tiles][16 rows][64], swizzled source
  {
    const int c = tid, rl = c >> 3, sl = c & 7;
    const int tl2 = rl >> 4, prow = rl & 15;
    const int gs = sl ^ (prow & 7);
    gl_lds16(g.W[8] + (size_t)(n*16 + prow)*H + tl2*64 + gs*8,
             &lds[L_WP + (tid>>6)*512]);
  }
  asm volatile("s_waitcnt vmcnt(0)" ::: "memory");
  __syncthreads();

  float cE[2][4]  = {{0,0,0,0},{0,0,0,0}};
  float cD0[1][4] = {{0,0,0,0}};
  float cD1[1][4] = {{0,0,0,0}};

  for (int p = 0; p < 388; ++p){
    if (role == 0){
      if (p < 128){
        const int t = p, pr = t&1, pw = (t+1)&1;
        Ph J{g.x, t, nullptr, P(0+pr), 2, 4, g.W[0], g.W[1], D, H,
             gb0, g.bs, P(0+pw), 0, nullptr, nullptr, 0};
        run_layer<2>(lds, J, tid, w, lr, lc, n, cE);
      } else if (p >= 129 && p <= 384){
        const int q = p-129, t = q>>1, h = q&1, pr = t&1, pw = (t+1)&1;
        const u32* a1 = (t == 0) ? P(2) : P(6+pr);
        Ph J{nullptr, 0, a1, P(4+pr), 4, 4, g.W[4], g.W[5], H, H,
             gb0 + (size_t)h*64, g.bs + 2048, P(4+pw),
             (t >= 1) ? 1 : 0, g.bout, g.out, t-1};
        if (h == 0) run_layer<1>(lds, J, tid, w, lr, lc, n, cD0);
        else        run_layer<1>(lds, J, tid, w, lr, lc, n, cD1);
      } else if (p >= 386){
        // tail proj(tau=127) for half h = p-386: junk LSTM into sink plane
        const int h = p - 386;
        Ph J{nullptr, 0, P(6), P(4), 4, 4, g.W[4], g.W[5], H, H,
             gb0 + (size_t)h*64, g.bs + 2048, P(8), 1, g.bout, g.out, 127};
        float cj[1][4] = {{0,0,0,0}};
        run_layer<1>(lds, J, tid, w, lr, lc, n, cj);
      }
      // p==128, p==385 idle
    } else {
      if (p >= 1 && p <= 128){
        const int t = p-1, pr = t&1, pw = (t+1)&1;
        Ph J{nullptr, 0, P(0+pw), P(2+pr), 4, 4, g.W[2], g.W[3], H, H,
             gb0, g.bs + 1024, P(2+pw), 0, nullptr, nullptr, 0};
        run_layer<2>(lds, J, tid, w, lr, lc, n, cE);
      } else if (p >= 130 && p <= 385){
        const int r2 = p-130, t = r2>>1, h = r2&1, pr = t&1, pw = (t+1)&1;
        Ph J{nullptr, 0, P(4+pw), P(6+pr), 4, 4, g.W[6], g.W[7], H, H,
             gb0 + (size_t)h*64, g.bs + 3072, P(6+pw), 0, nullptr, nullptr, 0};
        if (h == 0) run_layer<1>(lds, J, tid, w, lr, lc, n, cD0);
        else        run_layer<1>(lds, J, tid, w, lr, lc, n, cD1);
      }
    }
    // slice barrier: store-only arrival + parallel flag poll (no RMW, no fences)
    __syncthreads();                       // drains each wave's vmem before barrier
    if (tid == 0) ast32(&flg[idx], (u32)(p + 1));
    if (tid < 16){
      while (ald32(&flg[tid]) < (u32)(p + 1))
        __builtin_amdgcn_s_sleep(1);
    }
    __syncthreads();
  }
}

extern "C" void kernel_launch(void* const* d_in, const int* in_sizes, int n_in,
                              void* d_out, int out_size, void* d_ws, size_t ws_size,
                              hipStream_t stream)
{
  const float* x     = (const float*)d_in[0];
  const float* eWih0 = (const float*)d_in[1];
  const float* eWhh0 = (const float*)d_in[2];
  const float* ebih0 = (const float*)d_in[3];
  const float* ebhh0 = (const float*)d_in[4];
  const float* eWih1 = (const float*)d_in[5];
  const float* eWhh1 = (const float*)d_in[6];
  const float* ebih1 = (const float*)d_in[7];
  const float* ebhh1 = (const float*)d_in[8];
  const float* dWih0 = (const float*)d_in[9];
  const float* dWhh0 = (const float*)d_in[10];
  const float* dbih0 = (const float*)d_in[11];
  const float* dbhh0 = (const float*)d_in[12];
  const float* dWih1 = (const float*)d_in[13];
  const float* dWhh1 = (const float*)d_in[14];
  const float* dbih1 = (const float*)d_in[15];
  const float* dbhh1 = (const float*)d_in[16];
  const float* Wout  = (const float*)d_in[17];
  const float* bout  = (const float*)d_in[18];
  float* out = (float*)d_out;

  // ---- workspace layout ----
  u16* wc = (u16*)d_ws;
  const int szW[9] = {4*H*D, 4*H*H, 4*H*H, 4*H*H, 4*H*H, 4*H*H, 4*H*H, 4*H*H, D*H};
  const float* srcW[9] = {eWih0,eWhh0,eWih1,eWhh1,dWih0,dWhh0,dWih1,dWhh1,Wout};
  u16* dstW[9]; size_t woff = 0;
  for (int i = 0; i < 9; ++i){ dstW[i] = wc + woff; woff += (size_t)szW[i]; }
  woff = (woff + 7) & ~(size_t)7;
  float* bs = (float*)(wc + woff);
  u32* pl    = (u32*)(bs + 4*1024);      // planes P0..P8 (9*PH u32), then flags
  u32* flags = pl + 9*PH;                // 16 slices x 16 u32

  for (int i = 0; i < 9; ++i)
    cvtk<<<dim3((szW[i]+1023)/1024), dim3(256), 0, stream>>>(srcW[i], dstW[i], szW[i]);
  addk<<<dim3(4), dim3(256), 0, stream>>>(ebih0, ebhh0, bs,        1024);
  addk<<<dim3(4), dim3(256), 0, stream>>>(ebih1, ebhh1, bs + 1024, 1024);
  addk<<<dim3(4), dim3(256), 0, stream>>>(dbih0, dbhh0, bs + 2048, 1024);
  addk<<<dim3(4), dim3(256), 0, stream>>>(dbih1, dbhh1, bs + 3072, 1024);
  // zero ALL planes AND flags every call (graph replays included)
  hipMemsetAsync(pl, 0, (9*PH + 1024) * sizeof(u32), stream);

  GG g;
  g.x = x;
  for (int i = 0; i < 9; ++i) g.W[i] = dstW[i];
  g.bs = bs; g.bout = bout;
  g.P = pl; g.out = out; g.flags = flags;

  persist<<<dim3(256), dim3(512), 0, stream>>>(g);
}